// Round 1
// baseline (455.134 us; speedup 1.0000x reference)
//
#include <hip/hip_runtime.h>

// BaseGNN: 2-layer GraphConv (norm='both', leaky_relu) + mean-pool over rows
// [0..order] + final linear. Output: 64 floats.
//
// Optimization structure:
//  - Only h2 rows <= order are pooled -> layer-2 edge pass filters dst<=order.
//  - h1 only read at src of those edges -> bitmap S = {src | dst<=order};
//    layer-1 edge pass and GEMM1 filter by S (~8x less heavy work).
//  - o_is folded into gathered features; i_is folded into GEMM epilogue;
//    next layer's o_is folded into h1 write.

#define C 64

__global__ void k_deg_bitmap(const int* __restrict__ src, const int* __restrict__ dst,
                             float* __restrict__ degf_out, float* __restrict__ degf_in,
                             unsigned int* __restrict__ bitmap,
                             const int* __restrict__ order_p, int E) {
    int e = blockIdx.x * blockDim.x + threadIdx.x;
    if (e >= E) return;
    int s = src[e], d = dst[e];
    atomicAdd(&degf_out[s], 1.0f);
    atomicAdd(&degf_in[d], 1.0f);
    if (d <= *order_p) atomicOr(&bitmap[s >> 5], 1u << (s & 31));
}

__global__ void k_rsqrt(float* __restrict__ o_is, float* __restrict__ i_is, int N) {
    int v = blockIdx.x * blockDim.x + threadIdx.x;
    if (v >= N) return;
    o_is[v] = rsqrtf(fmaxf(o_is[v], 1.0f));
    i_is[v] = rsqrtf(fmaxf(i_is[v], 1.0f));
}

// A[v][c] = feat[v][c] * o_is[v], float4-vectorized (one float4 per thread)
__global__ void k_scale_feat(const float* __restrict__ feat, const float* __restrict__ o_is,
                             float* __restrict__ A, int n4) {
    int i = blockIdx.x * blockDim.x + threadIdx.x;
    if (i >= n4) return;
    int node = i >> 4;                 // 16 float4 per node row (C=64)
    float s = o_is[node];
    float4 v = reinterpret_cast<const float4*>(feat)[i];
    v.x *= s; v.y *= s; v.z *= s; v.w *= s;
    reinterpret_cast<float4*>(A)[i] = v;
}

// Scatter-add H[src] row into agg[dst] row. 16 lanes per edge, float4 each.
// use_bitmap=1: keep edges whose dst is in bitmap (layer 1)
// use_bitmap=0: keep edges with dst <= *order_p (layer 2)
__global__ void k_edge_agg(const int* __restrict__ src, const int* __restrict__ dst,
                           const float* __restrict__ H, float* __restrict__ agg,
                           const unsigned int* __restrict__ bitmap,
                           const int* __restrict__ order_p, int E, int use_bitmap) {
    int gid = blockIdx.x * blockDim.x + threadIdx.x;
    int e = gid >> 4;
    int lane = gid & 15;
    if (e >= E) return;
    int d = dst[e];
    if (use_bitmap) {
        if (!((bitmap[d >> 5] >> (d & 31)) & 1u)) return;
    } else {
        if (d > *order_p) return;
    }
    int s = src[e];
    float4 v = reinterpret_cast<const float4*>(H)[s * 16 + lane];
    float* a = agg + d * C + lane * 4;
    atomicAdd(a + 0, v.x);
    atomicAdd(a + 1, v.y);
    atomicAdd(a + 2, v.z);
    atomicAdd(a + 3, v.w);
}

// Per-wave 64x64 row-GEMM: out[n][c] = leaky( i_is[n]*sum_k agg[n][k]*W[k][c] + b[c] )
// mode 0 (layer 1): only nodes in bitmap; multiply result by o_is[n] (next-layer fold)
// mode 1 (layer 2): only nodes <= *order_p; no o_is fold
__global__ void __launch_bounds__(256) k_gemm(
        const float* __restrict__ agg, const float* __restrict__ W,
        const float* __restrict__ bias, const float* __restrict__ i_is,
        const float* __restrict__ o_is, float* __restrict__ out,
        const unsigned int* __restrict__ bitmap, const int* __restrict__ order_p,
        int N, int mode) {
    __shared__ float Wl[C][C];   // 16 KiB
    int t = threadIdx.x;
    for (int i = t; i < C * C; i += 256) Wl[i >> 6][i & 63] = W[i];
    int w = t >> 6;              // wave id within block (wave64)
    int c = t & 63;
    int node = blockIdx.x * 4 + w;
    bool active = node < N;
    if (active) {
        if (mode == 0) active = (bitmap[node >> 5] >> (node & 31)) & 1u;
        else           active = node <= *order_p;
    }
    __syncthreads();             // single barrier; safe to return after
    if (!active) return;
    const float* arow = agg + (size_t)node * C;
    float acc = 0.f;
#pragma unroll
    for (int k = 0; k < C; ++k) acc = fmaf(arow[k], Wl[k][c], acc);
    acc = acc * i_is[node] + bias[c];
    acc = acc > 0.f ? acc : 0.01f * acc;
    if (mode == 0) acc *= o_is[node];
    out[(size_t)node * C + c] = acc;
}

// pooled[c] = mean(h2[0..order][c]); out = pooled @ Wl + bl. Single block.
__global__ void k_pool_final(const float* __restrict__ h2, const float* __restrict__ Wlin,
                             const float* __restrict__ blin, const int* __restrict__ order_p,
                             float* __restrict__ out) {
    __shared__ float partial[4][C];
    __shared__ float pooled[C];
    int t = threadIdx.x;
    int g = t >> 6, c = t & 63;
    int P = *order_p + 1;
    float s = 0.f;
    for (int r = g; r < P; r += 4) s += h2[(size_t)r * C + c];
    partial[g][c] = s;
    __syncthreads();
    if (t < C) {
        float tot = partial[0][t] + partial[1][t] + partial[2][t] + partial[3][t];
        pooled[t] = tot / (float)P;
    }
    __syncthreads();
    if (t < C) {
        float acc = blin[t];
#pragma unroll
        for (int k = 0; k < C; ++k) acc = fmaf(pooled[k], Wlin[k * C + t], acc);
        out[t] = acc;
    }
}

extern "C" void kernel_launch(void* const* d_in, const int* in_sizes, int n_in,
                              void* d_out, int out_size, void* d_ws, size_t ws_size,
                              hipStream_t stream) {
    const int*   src     = (const int*)d_in[0];
    const int*   dst     = (const int*)d_in[1];
    const float* feat    = (const float*)d_in[2];
    const float* W1      = (const float*)d_in[3];
    const float* b1      = (const float*)d_in[4];
    const float* W2      = (const float*)d_in[5];
    const float* b2      = (const float*)d_in[6];
    const float* Wlin    = (const float*)d_in[7];
    const float* blin    = (const float*)d_in[8];
    const int*   order_p = (const int*)d_in[9];

    int E = in_sizes[0];
    int N = in_sizes[2] / C;

    // Workspace layout
    char* ws = (char*)d_ws;
    size_t o_off  = 0;
    size_t i_off  = (size_t)N * 4;
    size_t bm_off = (size_t)2 * N * 4;
    size_t bm_bytes = ((size_t)(N + 31) / 32) * 4;
    size_t A_off = ((bm_off + bm_bytes + 255) / 256) * 256;
    size_t B_off = A_off + (size_t)N * C * 4;
    // total = B_off + N*C*4  (~52 MB for N=100k)

    float*        o_is   = (float*)(ws + o_off);
    float*        i_is   = (float*)(ws + i_off);
    unsigned int* bitmap = (unsigned int*)(ws + bm_off);
    float*        A      = (float*)(ws + A_off);   // h_scaled -> h1s -> h2
    float*        B      = (float*)(ws + B_off);   // agg buffer

    // zero degree counters + bitmap (contiguous prefix), and agg buffer
    hipMemsetAsync(ws, 0, A_off, stream);
    hipMemsetAsync(B, 0, (size_t)N * C * 4, stream);

    k_deg_bitmap<<<(E + 255) / 256, 256, 0, stream>>>(src, dst, o_is, i_is, bitmap, order_p, E);
    k_rsqrt<<<(N + 255) / 256, 256, 0, stream>>>(o_is, i_is, N);
    k_scale_feat<<<(N * 16 + 255) / 256, 256, 0, stream>>>(feat, o_is, A, N * 16);

    // layer 1: scatter only into bitmap dsts, GEMM only bitmap rows
    int edge_threads = E * 16;
    k_edge_agg<<<(edge_threads + 255) / 256, 256, 0, stream>>>(src, dst, A, B, bitmap, order_p, E, 1);
    k_gemm<<<(N + 3) / 4, 256, 0, stream>>>(B, W1, b1, i_is, o_is, A, bitmap, order_p, N, 0);

    // layer 2: scatter only into dst<=order, GEMM only rows<=order
    hipMemsetAsync(B, 0, (size_t)N * C * 4, stream);
    k_edge_agg<<<(edge_threads + 255) / 256, 256, 0, stream>>>(src, dst, A, B, bitmap, order_p, E, 0);
    k_gemm<<<(N + 3) / 4, 256, 0, stream>>>(B, W2, b2, i_is, nullptr, A, bitmap, order_p, N, 1);

    k_pool_final<<<1, 256, 0, stream>>>(A, Wlin, blin, order_p, (float*)d_out);
}